// Round 8
// baseline (140.261 us; speedup 1.0000x reference)
//
#include <hip/hip_runtime.h>
#include <hip/hip_bf16.h>

// B=256, x:[B,80,14,14] f32, w1:[512,80], b1:[512], w2:[512,512], b2:[512],
// w3:[512,4,14,14], fc_w:[80,2048], fc_b:[80] -> out:[B,80] f32.
// h2 = (w2@w1) x + (w2@b1+b2); bias folded as k-channel 80 (x col 80 = 1.0).
#define CIN 80
#define NSP 196
#define HWP 208        // hw padded 196->208 (13 n-tiles of 16)
#define KP  96         // k padded 80(+bias)->96 (3 MFMA k-steps of 32)

#define NBA 4096       // Wc k-split: 128 o-quads x 32 k-chunks, 16 MAC/thread
#define NBB 1024       // x-prep: 256 b x 4 hw-quarters
#define NBC 512        // w3 -> bf16 transpose
#define NBD 64         // fc_w -> bf16 transpose
#define NBE 16         // out init

typedef __attribute__((ext_vector_type(8))) short  short8;
typedef __attribute__((ext_vector_type(4))) float  floatx4;
typedef __attribute__((ext_vector_type(4))) unsigned short ushort4v;

static __device__ __forceinline__ unsigned short f2b(float f) {
    __hip_bfloat16 h = __float2bfloat16(f);
    return *(unsigned short*)&h;
}
static __device__ __forceinline__ float b2f(unsigned short u) {
    unsigned int x = ((unsigned int)u) << 16;
    float f; __builtin_memcpy(&f, &x, 4); return f;
}

// ---- kPre: all prep in ONE dispatch. Wc via wide k-split + atomics ----------
__global__ __launch_bounds__(384) void kPre(
    const float* __restrict__ x,  const float* __restrict__ w1,
    const float* __restrict__ b1, const float* __restrict__ w2,
    const float* __restrict__ b2, const float* __restrict__ w3,
    const float* __restrict__ fc_w, const float* __restrict__ fc_b,
    float* __restrict__ Wcf, unsigned short* __restrict__ xbf,
    unsigned short* __restrict__ w3tb, unsigned short* __restrict__ fctb,
    float* __restrict__ out)
{
    __shared__ float tile[80 * 53];
    const int blk = blockIdx.x, t = threadIdx.x;

    if (blk < NBA) {
        // Wcf[o][96] f32 += w2[o][m0:m0+16] @ (w1|b1)[m0:m0+16][lc]
        const int o4 = blk >> 5, kc = blk & 31;
        const int lc = t % 96, oi = t / 96;
        const int o = o4 * 4 + oi;
        const int m0 = kc * 16;
        if (lc <= CIN) {
            const float* __restrict__ w2p = w2 + (size_t)o * 512 + m0;
            float part = 0.f;
            if (lc < CIN) {
                const float* __restrict__ w1p = w1 + (size_t)m0 * CIN + lc;
                #pragma unroll
                for (int i = 0; i < 16; ++i)
                    part = fmaf(w2p[i], w1p[(size_t)i * CIN], part);
            } else {
                #pragma unroll
                for (int i = 0; i < 16; ++i)
                    part = fmaf(w2p[i], b1[m0 + i], part);
                if (kc == 31) part += b2[o];
            }
            atomicAdd(Wcf + o * KP + lc, part);   // cols 81..95 stay memset-0
        }
    } else if (blk < NBA + NBB) {
        // x [b][80][196] f32 -> xbf [b][208][96] bf16 (col80=1, all pads=0)
        const int r = blk - NBA;
        const int b = r >> 2, qt = r & 3, hw0 = qt * 52;
        for (int idx = t; idx < 80 * 52; idx += 384) {
            const int k = idx / 52, hl = idx - k * 52;
            const int hw = hw0 + hl;
            tile[k * 53 + hl] = (hw < NSP) ? x[(size_t)b * CIN * NSP + k * NSP + hw] : 0.f;
        }
        __syncthreads();
        unsigned short* __restrict__ ob = xbf + (size_t)b * HWP * KP;
        for (int idx = t; idx < 52 * 24; idx += 384) {   // 24 ushort4 per row
            const int hl = idx / 24, kq = idx - hl * 24;
            const int hw = hw0 + hl;
            ushort4v v;
            #pragma unroll
            for (int j = 0; j < 4; ++j) {
                const int k = kq * 4 + j;
                float f = 0.f;
                if (hw < NSP) {
                    if (k < CIN) f = tile[k * 53 + hl];
                    else if (k == CIN) f = 1.f;        // bias channel
                }
                v[j] = f2b(f);
            }
            *(ushort4v*)(ob + (size_t)hw * KP + kq * 4) = v;
        }
    } else if (blk < NBA + NBB + NBC) {
        // w3 [g][4][196] -> w3tb [g][208][4] bf16, hw zero-padded
        const int g = blk - NBA - NBB;
        if (t < HWP) {
            ushort4v v;
            #pragma unroll
            for (int o = 0; o < 4; ++o)
                v[o] = f2b((t < NSP) ? w3[(size_t)g * 4 * NSP + o * NSP + t] : 0.f);
            *(ushort4v*)(w3tb + ((size_t)g * HWP + t) * 4) = v;
        }
    } else if (blk < NBA + NBB + NBC + NBD) {
        // fc_w [80][2048] -> fctb [2048][80] bf16
        const int base = (blk - NBA - NBB - NBC) * 2560;
        for (int i = t; i < 2560; i += 384) {
            const int idx = base + i;
            const int k = idx / CIN, l = idx - k * CIN;
            fctb[idx] = f2b(fc_w[(size_t)l * 2048 + k]);
        }
    } else {
        // out init = fc_b broadcast
        const int base = (blk - NBA - NBB - NBC - NBD) * 1280;
        for (int i = t; i < 1280; i += 384) {
            const int idx = base + i;
            out[idx] = fc_b[idx - (idx / CIN) * CIN];
        }
    }
}

// ---- kM: fused GEMM + conv3 + relu + fc-partial -----------------------------
// block = (2 batches, 64-group chunk); wave = 16 groups. Software-pipelined
// nt-loop: load nt+1's x/w3 while computing nt (MLP without full unroll).
__global__ __launch_bounds__(256) void kM(
    const unsigned short* __restrict__ xbf, const float* __restrict__ Wcf,
    const unsigned short* __restrict__ w3tb, const unsigned short* __restrict__ fctb,
    float* __restrict__ out)
{
    __shared__ float gl[2 * 256];     // [bi][glocal*4+o]
    const int bp = blockIdx.x, gc = blockIdx.y;
    const int t = threadIdx.x;
    const int w = t >> 6, lane = t & 63;
    const int col = lane & 15, quad = lane >> 4;
    const int g0 = gc * 64 + w * 16;
    const int b0 = bp * 2;

    // A-frags: 16 groups x 96 k; load f32 Wc, convert to bf16 (12 VGPRs live)
    short8 A[3];
    {
        const float* __restrict__ ap = Wcf + (size_t)(g0 + col) * KP + quad * 8;
        #pragma unroll
        for (int ks = 0; ks < 3; ++ks) {
            const floatx4 lo = *(const floatx4*)(ap + ks * 32);
            const floatx4 hi = *(const floatx4*)(ap + ks * 32 + 4);
            short8 s;
            #pragma unroll
            for (int j = 0; j < 4; ++j) {
                s[j]     = (short)f2b(lo[j]);
                s[4 + j] = (short)f2b(hi[j]);
            }
            A[ks] = s;
        }
    }

    float p[2][4][4];   // conv3 partials [bi][r][o]
    #pragma unroll
    for (int bi = 0; bi < 2; ++bi)
        #pragma unroll
        for (int r = 0; r < 4; ++r)
            #pragma unroll
            for (int o = 0; o < 4; ++o) p[bi][r][o] = 0.f;

    const unsigned short* __restrict__ xb =
        xbf + ((size_t)b0 * HWP + col) * KP + quad * 8;
    const unsigned short* __restrict__ wb =
        w3tb + ((size_t)(g0 + quad * 4) * HWP + col) * 4;

    // pipeline regs: current iteration's x-frags and w3-rows
    short8 cx[2][3];
    ushort4v cw[4];
    #pragma unroll
    for (int bi = 0; bi < 2; ++bi) {
        const unsigned short* __restrict__ xp = xb + (size_t)bi * HWP * KP;
        cx[bi][0] = *(const short8*)(xp);
        cx[bi][1] = *(const short8*)(xp + 32);
        cx[bi][2] = *(const short8*)(xp + 64);
    }
    #pragma unroll
    for (int r = 0; r < 4; ++r)
        cw[r] = *(const ushort4v*)(wb + (size_t)r * HWP * 4);

    #pragma unroll 1
    for (int nt = 0; nt < 13; ++nt) {
        // issue next iteration's loads first (clamped on last iter: harmless re-load)
        const int ntn = (nt < 12) ? nt + 1 : 12;
        short8 nx[2][3];
        ushort4v nw[4];
        #pragma unroll
        for (int bi = 0; bi < 2; ++bi) {
            const unsigned short* __restrict__ xp = xb + ((size_t)bi * HWP + ntn * 16) * KP;
            nx[bi][0] = *(const short8*)(xp);
            nx[bi][1] = *(const short8*)(xp + 32);
            nx[bi][2] = *(const short8*)(xp + 64);
        }
        #pragma unroll
        for (int r = 0; r < 4; ++r)
            nw[r] = *(const ushort4v*)(wb + ((size_t)r * HWP + ntn * 16) * 4);

        // compute with current regs
        float wv[4][4];
        #pragma unroll
        for (int r = 0; r < 4; ++r) {
            wv[r][0] = b2f(cw[r][0]); wv[r][1] = b2f(cw[r][1]);
            wv[r][2] = b2f(cw[r][2]); wv[r][3] = b2f(cw[r][3]);
        }
        #pragma unroll
        for (int bi = 0; bi < 2; ++bi) {
            floatx4 acc = {0.f, 0.f, 0.f, 0.f};
            acc = __builtin_amdgcn_mfma_f32_16x16x32_bf16(A[0], cx[bi][0], acc, 0, 0, 0);
            acc = __builtin_amdgcn_mfma_f32_16x16x32_bf16(A[1], cx[bi][1], acc, 0, 0, 0);
            acc = __builtin_amdgcn_mfma_f32_16x16x32_bf16(A[2], cx[bi][2], acc, 0, 0, 0);
            // C/D: col(hw)=lane&15, row(g)=quad*4+r  [m89-verified]
            #pragma unroll
            for (int r = 0; r < 4; ++r) {
                p[bi][r][0] = fmaf(acc[r], wv[r][0], p[bi][r][0]);
                p[bi][r][1] = fmaf(acc[r], wv[r][1], p[bi][r][1]);
                p[bi][r][2] = fmaf(acc[r], wv[r][2], p[bi][r][2]);
                p[bi][r][3] = fmaf(acc[r], wv[r][3], p[bi][r][3]);
            }
        }
        // rotate pipeline
        #pragma unroll
        for (int bi = 0; bi < 2; ++bi) {
            cx[bi][0] = nx[bi][0]; cx[bi][1] = nx[bi][1]; cx[bi][2] = nx[bi][2];
        }
        #pragma unroll
        for (int r = 0; r < 4; ++r) cw[r] = nw[r];
    }

    // reduce over 16 hw-lanes, relu, stash in LDS
    #pragma unroll
    for (int bi = 0; bi < 2; ++bi)
        #pragma unroll
        for (int r = 0; r < 4; ++r) {
            float q0 = p[bi][r][0], q1 = p[bi][r][1], q2 = p[bi][r][2], q3 = p[bi][r][3];
            #pragma unroll
            for (int s = 8; s >= 1; s >>= 1) {
                q0 += __shfl_down(q0, s, 16);
                q1 += __shfl_down(q1, s, 16);
                q2 += __shfl_down(q2, s, 16);
                q3 += __shfl_down(q3, s, 16);
            }
            if (col == 0) {
                const int glocal = w * 16 + quad * 4 + r;
                floatx4 ov = {fmaxf(q0, 0.f), fmaxf(q1, 0.f), fmaxf(q2, 0.f), fmaxf(q3, 0.f)};
                *(floatx4*)(gl + bi * 256 + glocal * 4) = ov;
            }
        }
    __syncthreads();

    // fc partial over this block's 256 k-cols (k = gc*256 + klocal), 2 batches
    if (t < 160) {
        const int l = t % CIN, half = t / CIN;
        const unsigned short* __restrict__ fr =
            fctb + (size_t)(gc * 256 + half * 128) * CIN + l;
        const float* __restrict__ gp = gl + half * 128;
        float s0 = 0.f, s1 = 0.f;
        #pragma unroll 4
        for (int kk = 0; kk < 128; ++kk) {
            const float fv = b2f(fr[(size_t)kk * CIN]);
            s0 = fmaf(gp[kk      ], fv, s0);
            s1 = fmaf(gp[kk + 256], fv, s1);
        }
        atomicAdd(out + (b0 + 0) * CIN + l, s0);
        atomicAdd(out + (b0 + 1) * CIN + l, s1);
    }
}

extern "C" void kernel_launch(void* const* d_in, const int* in_sizes, int n_in,
                              void* d_out, int out_size, void* d_ws, size_t ws_size,
                              hipStream_t stream) {
    const float* x    = (const float*)d_in[0];
    const float* w1   = (const float*)d_in[1];
    const float* b1   = (const float*)d_in[2];
    const float* w2   = (const float*)d_in[3];
    const float* b2   = (const float*)d_in[4];
    const float* w3   = (const float*)d_in[5];
    const float* fc_w = (const float*)d_in[6];
    const float* fc_b = (const float*)d_in[7];
    float* out = (float*)d_out;

    const int B = in_sizes[0] / (CIN * NSP);   // 256

    // workspace: xbf | Wcf | w3tb | fctb  (~11.6 MB)
    char* ws = (char*)d_ws;
    unsigned short* xbf = (unsigned short*)ws;                  // B*208*96*2
    size_t off = (size_t)B * HWP * KP * 2;
    float* Wcf = (float*)(ws + off);                   off += 512 * KP * 4;
    unsigned short* w3tb = (unsigned short*)(ws + off); off += (size_t)512 * HWP * 4 * 2;
    unsigned short* fctb = (unsigned short*)(ws + off);         // 2048*80*2

    hipMemsetAsync(Wcf, 0, 512 * KP * 4, stream);
    kPre<<<NBA + NBB + NBC + NBD + NBE, 384, 0, stream>>>(
        x, w1, b1, w2, b2, w3, fc_w, fc_b, Wcf, xbf, w3tb, fctb, out);
    kM<<<dim3(B / 2, 8), 256, 0, stream>>>(xbf, Wcf, w3tb, fctb, out);
}

// Round 9
// 139.351 us; speedup vs baseline: 1.0065x; 1.0065x over previous
//
#include <hip/hip_runtime.h>
#include <hip/hip_bf16.h>

// B=256, x:[B,80,14,14] f32, w1:[512,80], b1:[512], w2:[512,512], b2:[512],
// w3:[512,4,14,14], fc_w:[80,2048], fc_b:[80] -> out:[B,80] f32.
// h2 = (w2@w1) x + (w2@b1+b2); bias folded as k-channel 80 (x col 80 = 1.0).
#define CIN 80
#define NSP 196
#define HWP 208        // hw padded 196->208 (13 n-tiles of 16)
#define KP  96         // k padded 80(+bias)->96 (3 MFMA k-steps of 32)
#define XST 104        // xs LDS row stride (elems): 52 dwords -> optimal 8-phase b128

#define NBA 4096       // Wc k-split: 128 o-quads x 32 k-chunks, 16 MAC/thread
#define NBB 1024       // x-prep: 256 b x 4 hw-quarters
#define NBC 512        // w3 -> bf16 transpose
#define NBD 64         // fc_w -> bf16 transpose
#define NBE 16         // out init

typedef __attribute__((ext_vector_type(8))) short  short8;
typedef __attribute__((ext_vector_type(4))) float  floatx4;
typedef __attribute__((ext_vector_type(4))) unsigned short ushort4v;

static __device__ __forceinline__ unsigned short f2b(float f) {
    __hip_bfloat16 h = __float2bfloat16(f);
    return *(unsigned short*)&h;
}
static __device__ __forceinline__ float b2f(unsigned short u) {
    unsigned int x = ((unsigned int)u) << 16;
    float f; __builtin_memcpy(&f, &x, 4); return f;
}

// ---- kPre: all prep in ONE dispatch. Wc via wide k-split + atomics ----------
__global__ __launch_bounds__(384) void kPre(
    const float* __restrict__ x,  const float* __restrict__ w1,
    const float* __restrict__ b1, const float* __restrict__ w2,
    const float* __restrict__ b2, const float* __restrict__ w3,
    const float* __restrict__ fc_w, const float* __restrict__ fc_b,
    float* __restrict__ Wcf, unsigned short* __restrict__ xbf,
    unsigned short* __restrict__ w3tb, unsigned short* __restrict__ fctb,
    float* __restrict__ out)
{
    __shared__ float tile[80 * 53];
    const int blk = blockIdx.x, t = threadIdx.x;

    if (blk < NBA) {
        // Wcf[o][96] f32 += w2[o][m0:m0+16] @ (w1|b1)[m0:m0+16][lc]
        const int o4 = blk >> 5, kc = blk & 31;
        const int lc = t % 96, oi = t / 96;
        const int o = o4 * 4 + oi;
        const int m0 = kc * 16;
        if (lc <= CIN) {
            const float* __restrict__ w2p = w2 + (size_t)o * 512 + m0;
            float part = 0.f;
            if (lc < CIN) {
                const float* __restrict__ w1p = w1 + (size_t)m0 * CIN + lc;
                #pragma unroll
                for (int i = 0; i < 16; ++i)
                    part = fmaf(w2p[i], w1p[(size_t)i * CIN], part);
            } else {
                #pragma unroll
                for (int i = 0; i < 16; ++i)
                    part = fmaf(w2p[i], b1[m0 + i], part);
                if (kc == 31) part += b2[o];
            }
            atomicAdd(Wcf + o * KP + lc, part);   // cols 81..95 stay memset-0
        }
    } else if (blk < NBA + NBB) {
        // x [b][80][196] f32 -> xbf [b][208][96] bf16 (col80=1, all pads=0)
        const int r = blk - NBA;
        const int b = r >> 2, qt = r & 3, hw0 = qt * 52;
        for (int idx = t; idx < 80 * 52; idx += 384) {
            const int k = idx / 52, hl = idx - k * 52;
            const int hw = hw0 + hl;
            tile[k * 53 + hl] = (hw < NSP) ? x[(size_t)b * CIN * NSP + k * NSP + hw] : 0.f;
        }
        __syncthreads();
        unsigned short* __restrict__ ob = xbf + (size_t)b * HWP * KP;
        for (int idx = t; idx < 52 * 24; idx += 384) {   // 24 ushort4 per row
            const int hl = idx / 24, kq = idx - hl * 24;
            const int hw = hw0 + hl;
            ushort4v v;
            #pragma unroll
            for (int j = 0; j < 4; ++j) {
                const int k = kq * 4 + j;
                float f = 0.f;
                if (hw < NSP) {
                    if (k < CIN) f = tile[k * 53 + hl];
                    else if (k == CIN) f = 1.f;        // bias channel
                }
                v[j] = f2b(f);
            }
            *(ushort4v*)(ob + (size_t)hw * KP + kq * 4) = v;
        }
    } else if (blk < NBA + NBB + NBC) {
        // w3 [g][4][196] -> w3tb [g][208][4] bf16, hw zero-padded
        const int g = blk - NBA - NBB;
        if (t < HWP) {
            ushort4v v;
            #pragma unroll
            for (int o = 0; o < 4; ++o)
                v[o] = f2b((t < NSP) ? w3[(size_t)g * 4 * NSP + o * NSP + t] : 0.f);
            *(ushort4v*)(w3tb + ((size_t)g * HWP + t) * 4) = v;
        }
    } else if (blk < NBA + NBB + NBC + NBD) {
        // fc_w [80][2048] -> fctb [2048][80] bf16
        const int base = (blk - NBA - NBB - NBC) * 2560;
        for (int i = t; i < 2560; i += 384) {
            const int idx = base + i;
            const int k = idx / CIN, l = idx - k * CIN;
            fctb[idx] = f2b(fc_w[(size_t)l * 2048 + k]);
        }
    } else {
        // out init = fc_b broadcast
        const int base = (blk - NBA - NBB - NBC - NBD) * 1280;
        for (int i = t; i < 1280; i += 384) {
            const int idx = base + i;
            out[idx] = fc_b[idx - (idx / CIN) * CIN];
        }
    }
}

// ---- kM: fused GEMM + conv3 + relu + fc-partial -----------------------------
// block = (b, 128-group chunk); 8 waves x 16 groups. x[b] staged ONCE in LDS
// (8x fewer global requests than per-wave global reads); w3 global, 1-deep pipe.
__global__ __launch_bounds__(512) void kM(
    const unsigned short* __restrict__ xbf, const float* __restrict__ Wcf,
    const unsigned short* __restrict__ w3tb, const unsigned short* __restrict__ fctb,
    float* __restrict__ out)
{
    __shared__ __align__(16) unsigned short xs[HWP * XST];  // 43264 B
    __shared__ float gl[512];                               // 2048 B
    const int b = blockIdx.x, gc = blockIdx.y;   // b fast: XCD spread, w3 slice cached/XCD
    const int t = threadIdx.x;

    // stage x[b]: global rows stride 96 (12 chunks of 16B) -> LDS rows stride 104
    {
        const ushort4v* __restrict__ src = (const ushort4v*)(xbf + (size_t)b * HWP * KP);
        for (int idx = t; idx < HWP * 24; idx += 512) {      // 24 ushort4 per row
            const int r = idx / 24, c = idx - r * 24;
            *(ushort4v*)(xs + r * XST + c * 4) = src[r * 24 + c];
        }
    }

    const int w = t >> 6, lane = t & 63;
    const int col = lane & 15, quad = lane >> 4;
    const int g0 = gc * 128 + w * 16;

    // A-frags: 16 groups x 96 k; load f32 Wc, convert to bf16 (12 VGPRs live)
    short8 A[3];
    {
        const float* __restrict__ ap = Wcf + (size_t)(g0 + col) * KP + quad * 8;
        #pragma unroll
        for (int ks = 0; ks < 3; ++ks) {
            const floatx4 lo = *(const floatx4*)(ap + ks * 32);
            const floatx4 hi = *(const floatx4*)(ap + ks * 32 + 4);
            short8 s;
            #pragma unroll
            for (int j = 0; j < 4; ++j) {
                s[j]     = (short)f2b(lo[j]);
                s[4 + j] = (short)f2b(hi[j]);
            }
            A[ks] = s;
        }
    }

    float p[4][4];   // conv3 partials [r][o]
    #pragma unroll
    for (int r = 0; r < 4; ++r)
        #pragma unroll
        for (int o = 0; o < 4; ++o) p[r][o] = 0.f;

    const unsigned short* __restrict__ wb =
        w3tb + ((size_t)(g0 + quad * 4) * HWP + col) * 4;
    const unsigned short* __restrict__ xrow = xs + col * XST + quad * 8;

    __syncthreads();   // staging complete

    // w3 pipeline: current rows preloaded
    ushort4v cw[4];
    #pragma unroll
    for (int r = 0; r < 4; ++r)
        cw[r] = *(const ushort4v*)(wb + (size_t)r * HWP * 4);

    #pragma unroll 1
    for (int nt = 0; nt < 13; ++nt) {
        // issue next w3 loads (clamped on last iter)
        const int ntn = (nt < 12) ? nt + 1 : 12;
        ushort4v nw[4];
        #pragma unroll
        for (int r = 0; r < 4; ++r)
            nw[r] = *(const ushort4v*)(wb + ((size_t)r * HWP + ntn * 16) * 4);

        // x frags from LDS (short latency)
        const unsigned short* __restrict__ xp = xrow + nt * 16 * XST;
        const short8 x0 = *(const short8*)(xp);
        const short8 x1 = *(const short8*)(xp + 32);
        const short8 x2 = *(const short8*)(xp + 64);
        floatx4 acc = {0.f, 0.f, 0.f, 0.f};
        acc = __builtin_amdgcn_mfma_f32_16x16x32_bf16(A[0], x0, acc, 0, 0, 0);
        acc = __builtin_amdgcn_mfma_f32_16x16x32_bf16(A[1], x1, acc, 0, 0, 0);
        acc = __builtin_amdgcn_mfma_f32_16x16x32_bf16(A[2], x2, acc, 0, 0, 0);

        // conv3 partials; C/D: col(hw)=lane&15, row(g)=quad*4+r  [m89-verified]
        #pragma unroll
        for (int r = 0; r < 4; ++r) {
            p[r][0] = fmaf(acc[r], b2f(cw[r][0]), p[r][0]);
            p[r][1] = fmaf(acc[r], b2f(cw[r][1]), p[r][1]);
            p[r][2] = fmaf(acc[r], b2f(cw[r][2]), p[r][2]);
            p[r][3] = fmaf(acc[r], b2f(cw[r][3]), p[r][3]);
        }
        #pragma unroll
        for (int r = 0; r < 4; ++r) cw[r] = nw[r];
    }

    // reduce over 16 hw-lanes, relu, stash in LDS
    #pragma unroll
    for (int r = 0; r < 4; ++r) {
        float q0 = p[r][0], q1 = p[r][1], q2 = p[r][2], q3 = p[r][3];
        #pragma unroll
        for (int s = 8; s >= 1; s >>= 1) {
            q0 += __shfl_down(q0, s, 16);
            q1 += __shfl_down(q1, s, 16);
            q2 += __shfl_down(q2, s, 16);
            q3 += __shfl_down(q3, s, 16);
        }
        if (col == 0) {
            const int glocal = w * 16 + quad * 4 + r;
            floatx4 ov = {fmaxf(q0, 0.f), fmaxf(q1, 0.f), fmaxf(q2, 0.f), fmaxf(q3, 0.f)};
            *(floatx4*)(gl + glocal * 4) = ov;
        }
    }
    __syncthreads();

    // fc partial over this block's 512 k-cols (k = gc*512 + klocal)
    if (t < 320) {
        const int l = t % CIN, q = t / CIN;          // 4 k-quarters of 128
        const unsigned short* __restrict__ fr =
            fctb + (size_t)(gc * 512 + q * 128) * CIN + l;
        const float* __restrict__ gp = gl + q * 128;
        float s = 0.f;
        #pragma unroll 4
        for (int kk = 0; kk < 128; ++kk)
            s = fmaf(gp[kk], b2f(fr[(size_t)kk * CIN]), s);
        atomicAdd(out + b * CIN + l, s);             // out pre-set to fc_b by kPre
    }
}

extern "C" void kernel_launch(void* const* d_in, const int* in_sizes, int n_in,
                              void* d_out, int out_size, void* d_ws, size_t ws_size,
                              hipStream_t stream) {
    const float* x    = (const float*)d_in[0];
    const float* w1   = (const float*)d_in[1];
    const float* b1   = (const float*)d_in[2];
    const float* w2   = (const float*)d_in[3];
    const float* b2   = (const float*)d_in[4];
    const float* w3   = (const float*)d_in[5];
    const float* fc_w = (const float*)d_in[6];
    const float* fc_b = (const float*)d_in[7];
    float* out = (float*)d_out;

    const int B = in_sizes[0] / (CIN * NSP);   // 256

    // workspace: xbf | Wcf | w3tb | fctb  (~11.6 MB)
    char* ws = (char*)d_ws;
    unsigned short* xbf = (unsigned short*)ws;                  // B*208*96*2
    size_t off = (size_t)B * HWP * KP * 2;
    float* Wcf = (float*)(ws + off);                   off += 512 * KP * 4;
    unsigned short* w3tb = (unsigned short*)(ws + off); off += (size_t)512 * HWP * 4 * 2;
    unsigned short* fctb = (unsigned short*)(ws + off);         // 2048*80*2

    hipMemsetAsync(Wcf, 0, 512 * KP * 4, stream);
    kPre<<<NBA + NBB + NBC + NBD + NBE, 384, 0, stream>>>(
        x, w1, b1, w2, b2, w3, fc_w, fc_b, Wcf, xbf, w3tb, fctb, out);
    kM<<<dim3(B, 4), 512, 0, stream>>>(xbf, Wcf, w3tb, fctb, out);
}

// Round 10
// 138.300 us; speedup vs baseline: 1.0142x; 1.0076x over previous
//
#include <hip/hip_runtime.h>
#include <hip/hip_bf16.h>

// B=256, x:[B,80,14,14] f32, w1:[512,80], b1:[512], w2:[512,512], b2:[512],
// w3:[512,4,14,14], fc_w:[80,2048], fc_b:[80] -> out:[B,80] f32.
// h2 = (w2@w1) x + (w2@b1+b2); bias folded as k-channel 80 (x col 80 = 1.0).
#define CIN 80
#define NSP 196
#define HWP 208        // hw padded 196->208 (13 n-tiles of 16)
#define KP  96         // k padded 80(+bias)->96 (3 MFMA k-steps of 32)
#define XST 104        // xs LDS row stride (ushorts)

#define NBA 4096       // Wc k-split: 128 o-quads x 32 k-chunks, 16 MAC/thread
#define NBB 1024       // x-prep: 256 b x 4 hw-quarters
#define NBC 512        // w3 -> bf16 transpose
#define NBD 64         // fc_w -> bf16 transpose
#define NBE 16         // out init

typedef __attribute__((ext_vector_type(8))) short  short8;
typedef __attribute__((ext_vector_type(4))) float  floatx4;
typedef __attribute__((ext_vector_type(4))) unsigned short ushort4v;

static __device__ __forceinline__ unsigned short f2b(float f) {
    __hip_bfloat16 h = __float2bfloat16(f);
    return *(unsigned short*)&h;
}
static __device__ __forceinline__ float b2f(unsigned short u) {
    unsigned int x = ((unsigned int)u) << 16;
    float f; __builtin_memcpy(&f, &x, 4); return f;
}

// ---- kPre: all prep in ONE dispatch. Wc via wide k-split + atomics ----------
__global__ __launch_bounds__(384) void kPre(
    const float* __restrict__ x,  const float* __restrict__ w1,
    const float* __restrict__ b1, const float* __restrict__ w2,
    const float* __restrict__ b2, const float* __restrict__ w3,
    const float* __restrict__ fc_w, const float* __restrict__ fc_b,
    float* __restrict__ Wcf, unsigned short* __restrict__ xbf,
    unsigned short* __restrict__ w3tb, unsigned short* __restrict__ fctb,
    float* __restrict__ out)
{
    __shared__ float tile[80 * 53];
    const int blk = blockIdx.x, t = threadIdx.x;

    if (blk < NBA) {
        // Wcf[o][96] f32 += w2[o][m0:m0+16] @ (w1|b1)[m0:m0+16][lc]
        const int o4 = blk >> 5, kc = blk & 31;
        const int lc = t % 96, oi = t / 96;
        const int o = o4 * 4 + oi;
        const int m0 = kc * 16;
        if (lc <= CIN) {
            const float* __restrict__ w2p = w2 + (size_t)o * 512 + m0;
            float part = 0.f;
            if (lc < CIN) {
                const float* __restrict__ w1p = w1 + (size_t)m0 * CIN + lc;
                #pragma unroll
                for (int i = 0; i < 16; ++i)
                    part = fmaf(w2p[i], w1p[(size_t)i * CIN], part);
            } else {
                #pragma unroll
                for (int i = 0; i < 16; ++i)
                    part = fmaf(w2p[i], b1[m0 + i], part);
                if (kc == 31) part += b2[o];
            }
            atomicAdd(Wcf + o * KP + lc, part);   // cols 81..95 stay memset-0
        }
    } else if (blk < NBA + NBB) {
        // x [b][80][196] f32 -> xbf [b][208][96] bf16 (col80=1, all pads=0)
        const int r = blk - NBA;
        const int b = r >> 2, qt = r & 3, hw0 = qt * 52;
        for (int idx = t; idx < 80 * 52; idx += 384) {
            const int k = idx / 52, hl = idx - k * 52;
            const int hw = hw0 + hl;
            tile[k * 53 + hl] = (hw < NSP) ? x[(size_t)b * CIN * NSP + k * NSP + hw] : 0.f;
        }
        __syncthreads();
        unsigned short* __restrict__ ob = xbf + (size_t)b * HWP * KP;
        for (int idx = t; idx < 52 * 24; idx += 384) {   // 24 ushort4 per row
            const int hl = idx / 24, kq = idx - hl * 24;
            const int hw = hw0 + hl;
            ushort4v v;
            #pragma unroll
            for (int j = 0; j < 4; ++j) {
                const int k = kq * 4 + j;
                float f = 0.f;
                if (hw < NSP) {
                    if (k < CIN) f = tile[k * 53 + hl];
                    else if (k == CIN) f = 1.f;        // bias channel
                }
                v[j] = f2b(f);
            }
            *(ushort4v*)(ob + (size_t)hw * KP + kq * 4) = v;
        }
    } else if (blk < NBA + NBB + NBC) {
        // w3 [g][4][196] -> w3tb [g][208][4] bf16, hw zero-padded
        const int g = blk - NBA - NBB;
        if (t < HWP) {
            ushort4v v;
            #pragma unroll
            for (int o = 0; o < 4; ++o)
                v[o] = f2b((t < NSP) ? w3[(size_t)g * 4 * NSP + o * NSP + t] : 0.f);
            *(ushort4v*)(w3tb + ((size_t)g * HWP + t) * 4) = v;
        }
    } else if (blk < NBA + NBB + NBC + NBD) {
        // fc_w [80][2048] -> fctb [2048][80] bf16
        const int base = (blk - NBA - NBB - NBC) * 2560;
        for (int i = t; i < 2560; i += 384) {
            const int idx = base + i;
            const int k = idx / CIN, l = idx - k * CIN;
            fctb[idx] = f2b(fc_w[(size_t)l * 2048 + k]);
        }
    } else {
        // out init = fc_b broadcast
        const int base = (blk - NBA - NBB - NBC - NBD) * 1280;
        for (int i = t; i < 1280; i += 384) {
            const int idx = base + i;
            out[idx] = fc_b[idx - (idx / CIN) * CIN];
        }
    }
}

// ---- kM: fused GEMM + conv3 + relu + fc-partial -----------------------------
// block = (b, 256-group half); 8 waves x 32 groups (2 m-tiles). Denser MFMA per
// wave: per nt = 3 ds_read + 6 MFMA + 32 w3-FMA. x[b] staged once in LDS.
__global__ __launch_bounds__(512) void kM(
    const unsigned short* __restrict__ xbf, const float* __restrict__ Wcf,
    const unsigned short* __restrict__ w3tb, const unsigned short* __restrict__ fctb,
    float* __restrict__ out)
{
    __shared__ __align__(16) unsigned short xs[HWP * XST];  // 43264 B
    __shared__ float gl[1024];                              // 4096 B
    const int b = blockIdx.x, gc = blockIdx.y;
    const int t = threadIdx.x;

    // stage x[b]: rows of 24 ushort4 (96 k) -> LDS rows stride 104
    {
        const ushort4v* __restrict__ src = (const ushort4v*)(xbf + (size_t)b * HWP * KP);
        for (int idx = t; idx < HWP * 24; idx += 512) {
            const int r = idx / 24, c = idx - r * 24;
            *(ushort4v*)(xs + r * XST + c * 4) = src[idx];
        }
    }

    const int w = t >> 6, lane = t & 63;
    const int col = lane & 15, quad = lane >> 4;
    const int gb = gc * 256 + w * 32;      // wave's absolute group base

    // A-frags: 2 m-tiles x 96 k; load f32 Wc, convert to bf16 (24 VGPRs)
    short8 A[2][3];
    #pragma unroll
    for (int mt = 0; mt < 2; ++mt) {
        const float* __restrict__ ap = Wcf + (size_t)(gb + mt * 16 + col) * KP + quad * 8;
        #pragma unroll
        for (int ks = 0; ks < 3; ++ks) {
            const floatx4 lo = *(const floatx4*)(ap + ks * 32);
            const floatx4 hi = *(const floatx4*)(ap + ks * 32 + 4);
            short8 s;
            #pragma unroll
            for (int j = 0; j < 4; ++j) {
                s[j]     = (short)f2b(lo[j]);
                s[4 + j] = (short)f2b(hi[j]);
            }
            A[mt][ks] = s;
        }
    }

    float p[2][4][4];   // conv3 partials [mt][r][o]
    #pragma unroll
    for (int mt = 0; mt < 2; ++mt)
        #pragma unroll
        for (int r = 0; r < 4; ++r)
            #pragma unroll
            for (int o = 0; o < 4; ++o) p[mt][r][o] = 0.f;

    const unsigned short* __restrict__ xrow = xs + col * XST + quad * 8;
    const unsigned short* __restrict__ wb0 =
        w3tb + ((size_t)(gb + quad * 4) * HWP + col) * 4;
    const unsigned short* __restrict__ wb1 =
        w3tb + ((size_t)(gb + 16 + quad * 4) * HWP + col) * 4;

    __syncthreads();   // staging complete

    #pragma unroll 1
    for (int nt = 0; nt < 13; ++nt) {
        // w3 loads for both m-tiles (issued up front; overlap the MFMA chain)
        ushort4v wv0[4], wv1[4];
        #pragma unroll
        for (int r = 0; r < 4; ++r) {
            wv0[r] = *(const ushort4v*)(wb0 + ((size_t)r * HWP + nt * 16) * 4);
            wv1[r] = *(const ushort4v*)(wb1 + ((size_t)r * HWP + nt * 16) * 4);
        }
        // x frags from LDS (shared by both m-tiles)
        const unsigned short* __restrict__ xp = xrow + nt * 16 * XST;
        const short8 x0 = *(const short8*)(xp);
        const short8 x1 = *(const short8*)(xp + 32);
        const short8 x2 = *(const short8*)(xp + 64);
        floatx4 a0 = {0.f, 0.f, 0.f, 0.f}, a1 = {0.f, 0.f, 0.f, 0.f};
        a0 = __builtin_amdgcn_mfma_f32_16x16x32_bf16(A[0][0], x0, a0, 0, 0, 0);
        a0 = __builtin_amdgcn_mfma_f32_16x16x32_bf16(A[0][1], x1, a0, 0, 0, 0);
        a0 = __builtin_amdgcn_mfma_f32_16x16x32_bf16(A[0][2], x2, a0, 0, 0, 0);
        a1 = __builtin_amdgcn_mfma_f32_16x16x32_bf16(A[1][0], x0, a1, 0, 0, 0);
        a1 = __builtin_amdgcn_mfma_f32_16x16x32_bf16(A[1][1], x1, a1, 0, 0, 0);
        a1 = __builtin_amdgcn_mfma_f32_16x16x32_bf16(A[1][2], x2, a1, 0, 0, 0);
        // conv3 partials; C/D: col(hw)=lane&15, row(g)=quad*4+r  [m89-verified]
        #pragma unroll
        for (int r = 0; r < 4; ++r) {
            p[0][r][0] = fmaf(a0[r], b2f(wv0[r][0]), p[0][r][0]);
            p[0][r][1] = fmaf(a0[r], b2f(wv0[r][1]), p[0][r][1]);
            p[0][r][2] = fmaf(a0[r], b2f(wv0[r][2]), p[0][r][2]);
            p[0][r][3] = fmaf(a0[r], b2f(wv0[r][3]), p[0][r][3]);
            p[1][r][0] = fmaf(a1[r], b2f(wv1[r][0]), p[1][r][0]);
            p[1][r][1] = fmaf(a1[r], b2f(wv1[r][1]), p[1][r][1]);
            p[1][r][2] = fmaf(a1[r], b2f(wv1[r][2]), p[1][r][2]);
            p[1][r][3] = fmaf(a1[r], b2f(wv1[r][3]), p[1][r][3]);
        }
    }

    // reduce over 16 hw-lanes, relu, stash in LDS
    #pragma unroll
    for (int mt = 0; mt < 2; ++mt)
        #pragma unroll
        for (int r = 0; r < 4; ++r) {
            float q0 = p[mt][r][0], q1 = p[mt][r][1], q2 = p[mt][r][2], q3 = p[mt][r][3];
            #pragma unroll
            for (int s = 8; s >= 1; s >>= 1) {
                q0 += __shfl_down(q0, s, 16);
                q1 += __shfl_down(q1, s, 16);
                q2 += __shfl_down(q2, s, 16);
                q3 += __shfl_down(q3, s, 16);
            }
            if (col == 0) {
                const int glocal = w * 32 + mt * 16 + quad * 4 + r;
                floatx4 ov = {fmaxf(q0, 0.f), fmaxf(q1, 0.f), fmaxf(q2, 0.f), fmaxf(q3, 0.f)};
                *(floatx4*)(gl + glocal * 4) = ov;
            }
        }
    __syncthreads();

    // fc partial over this block's 1024 k-cols (k = gc*1024 + klocal)
    if (t < 320) {
        const int l = t % CIN, q = t / CIN;          // 4 k-quarters of 256
        const unsigned short* __restrict__ fr =
            fctb + (size_t)(gc * 1024 + q * 256) * CIN + l;
        const float* __restrict__ gp = gl + q * 256;
        float s = 0.f;
        #pragma unroll 4
        for (int kk = 0; kk < 256; ++kk)
            s = fmaf(gp[kk], b2f(fr[(size_t)kk * CIN]), s);
        atomicAdd(out + b * CIN + l, s);             // out pre-set to fc_b by kPre
    }
}

extern "C" void kernel_launch(void* const* d_in, const int* in_sizes, int n_in,
                              void* d_out, int out_size, void* d_ws, size_t ws_size,
                              hipStream_t stream) {
    const float* x    = (const float*)d_in[0];
    const float* w1   = (const float*)d_in[1];
    const float* b1   = (const float*)d_in[2];
    const float* w2   = (const float*)d_in[3];
    const float* b2   = (const float*)d_in[4];
    const float* w3   = (const float*)d_in[5];
    const float* fc_w = (const float*)d_in[6];
    const float* fc_b = (const float*)d_in[7];
    float* out = (float*)d_out;

    const int B = in_sizes[0] / (CIN * NSP);   // 256

    // workspace: xbf | Wcf | w3tb | fctb  (~11.6 MB)
    char* ws = (char*)d_ws;
    unsigned short* xbf = (unsigned short*)ws;                  // B*208*96*2
    size_t off = (size_t)B * HWP * KP * 2;
    float* Wcf = (float*)(ws + off);                   off += 512 * KP * 4;
    unsigned short* w3tb = (unsigned short*)(ws + off); off += (size_t)512 * HWP * 4 * 2;
    unsigned short* fctb = (unsigned short*)(ws + off);         // 2048*80*2

    hipMemsetAsync(Wcf, 0, 512 * KP * 4, stream);
    kPre<<<NBA + NBB + NBC + NBD + NBE, 384, 0, stream>>>(
        x, w1, b1, w2, b2, w3, fc_w, fc_b, Wcf, xbf, w3tb, fctb, out);
    kM<<<dim3(B, 2), 512, 0, stream>>>(xbf, Wcf, w3tb, fctb, out);
}

// Round 11
// 129.296 us; speedup vs baseline: 1.0848x; 1.0696x over previous
//
#include <hip/hip_runtime.h>
#include <hip/hip_bf16.h>

// B=256, x:[B,80,14,14] f32, w1:[512,80], b1:[512], w2:[512,512], b2:[512],
// w3:[512,4,14,14], fc_w:[80,2048], fc_b:[80] -> out:[B,80] f32.
// h2 = (w2@w1) x + (w2@b1+b2); bias folded as k-channel 80 (x col 80 = 1.0).
#define CIN 80
#define NSP 196
#define HWP 208        // hw padded 196->208 (13 n-tiles of 16)
#define KP  96         // k padded 80(+bias)->96 (3 MFMA k-steps of 32)
#define XST 104        // xs LDS row stride (ushorts)

#define NBA 1024       // Wc partials: 128 o-quads x 8 k-chunks of 64 (atomic-free)
#define NBC 512        // w3 -> bf16 transpose
#define NBD 64         // fc_w -> bf16 transpose

typedef __attribute__((ext_vector_type(8))) short  short8;
typedef __attribute__((ext_vector_type(4))) float  floatx4;
typedef __attribute__((ext_vector_type(4))) unsigned short ushort4v;

static __device__ __forceinline__ unsigned short f2b(float f) {
    __hip_bfloat16 h = __float2bfloat16(f);
    return *(unsigned short*)&h;
}
static __device__ __forceinline__ float b2f(unsigned short u) {
    unsigned int x = ((unsigned int)u) << 16;
    float f; __builtin_memcpy(&f, &x, 4); return f;
}

// ---- kPre: Wc k-split partials (no atomics) + w3/fct transposes -------------
__global__ __launch_bounds__(384) void kPre(
    const float* __restrict__ w1, const float* __restrict__ b1,
    const float* __restrict__ w2, const float* __restrict__ w3,
    const float* __restrict__ fc_w,
    float* __restrict__ Wcf8, unsigned short* __restrict__ w3tb,
    unsigned short* __restrict__ fctb)
{
    const int blk = blockIdx.x, t = threadIdx.x;

    if (blk < NBA) {
        // Wcf8[kc][o][lc] = w2[o][m0:m0+64] @ (w1|b1)[m0:m0+64][lc]
        const int o4 = blk >> 3, kc = blk & 7, m0 = kc * 64;
        if (t < 324) {
            const int lc = t % 81, oi = t / 81;
            const int o = o4 * 4 + oi;
            const float* __restrict__ w2p = w2 + (size_t)o * 512 + m0;  // broadcast
            float part = 0.f;
            if (lc < CIN) {
                const float* __restrict__ w1p = w1 + (size_t)m0 * CIN + lc;
                #pragma unroll 8
                for (int i = 0; i < 64; ++i)
                    part = fmaf(w2p[i], w1p[(size_t)i * CIN], part);
            } else {
                #pragma unroll 8
                for (int i = 0; i < 64; ++i)
                    part = fmaf(w2p[i], b1[m0 + i], part);
            }
            Wcf8[((size_t)kc * 512 + o) * KP + lc] = part;   // only lc<=80 written
        }
    } else if (blk < NBA + NBC) {
        // w3 [g][4][196] -> w3tb [g][208][4] bf16, hw zero-padded
        const int g = blk - NBA;
        if (t < HWP) {
            ushort4v v;
            #pragma unroll
            for (int o = 0; o < 4; ++o)
                v[o] = f2b((t < NSP) ? w3[(size_t)g * 4 * NSP + o * NSP + t] : 0.f);
            *(ushort4v*)(w3tb + ((size_t)g * HWP + t) * 4) = v;
        }
    } else {
        // fc_w [80][2048] -> fctb [2048][80] bf16
        const int base = (blk - NBA - NBC) * 2560;   // 64 blocks * 2560 = 163840
        for (int i = t; i < 2560; i += 384) {
            const int idx = base + i;
            const int k = idx / CIN, l = idx - k * CIN;
            fctb[idx] = f2b(fc_w[(size_t)l * 2048 + k]);
        }
    }
}

// ---- kRed: Wcbf[512][96] bf16 = sum of 8 partials (+b2 on col 80, 0 pads) ---
__global__ __launch_bounds__(1024) void kRed(
    const float* __restrict__ Wcf8, const float* __restrict__ b2,
    unsigned short* __restrict__ Wcbf)
{
    const int idx = blockIdx.x * 1024 + threadIdx.x;   // 48 blocks = 512*96
    const int o = idx / KP, c = idx - o * KP;
    float s = 0.f;
    if (c <= CIN) {
        #pragma unroll
        for (int j = 0; j < 8; ++j)
            s += Wcf8[((size_t)j * 512 + o) * KP + c];
        if (c == CIN) s += b2[o];
    }
    Wcbf[idx] = f2b(s);
}

// ---- kM: one block per batch, ALL 512 groups. 1024 thr = 16 waves x 32 grp. -
// x[b] built in LDS from f32 x directly; w3tb/fctb per-XCD L2-pinned (shared by
// every CU); fc fully in-block -> no atomics, out written once.
__global__ __launch_bounds__(1024) void kM(
    const float* __restrict__ x, const unsigned short* __restrict__ Wcbf,
    const unsigned short* __restrict__ w3tb, const unsigned short* __restrict__ fctb,
    const float* __restrict__ fc_b, float* __restrict__ out)
{
    __shared__ __align__(16) unsigned short xs[HWP * XST];  // 43264 B
    __shared__ float gl[2048];                              // 8192 B
    const int b = blockIdx.x, t = threadIdx.x;

    // stage x[b]: [k][hw] f32 coalesced -> xs[hw][k] bf16 (one-time scatter)
    {
        const float* __restrict__ xb = x + (size_t)b * CIN * NSP;
        for (int idx = t; idx < CIN * NSP; idx += 1024) {
            const int k = idx / NSP, hw = idx - k * NSP;
            xs[hw * XST + k] = f2b(xb[idx]);
        }
        // k = 80 -> 1.0 (bias channel), 81..103 -> 0, for hw < 196
        for (int idx = t; idx < NSP * 24; idx += 1024) {
            const int hw = idx / 24, k = 80 + (idx - (idx / 24) * 24);
            xs[hw * XST + k] = (k == CIN) ? (unsigned short)0x3F80 : (unsigned short)0;
        }
        // hw pad rows 196..207: all-zero (conv3 n=12 tail contributes 0)
        for (int idx = t; idx < 12 * XST; idx += 1024) {
            const int hw = NSP + idx / XST, k = idx - (idx / XST) * XST;
            xs[hw * XST + k] = 0;
        }
    }

    const int w = t >> 6, lane = t & 63;
    const int col = lane & 15, quad = lane >> 4;
    const int gb = w * 32;                 // wave's group base (16 waves x 32 = 512)

    // A-frags: 2 m-tiles x 96 k, bf16 (24 VGPRs), from L2-hot Wcbf
    short8 A[2][3];
    #pragma unroll
    for (int mt = 0; mt < 2; ++mt) {
        const unsigned short* __restrict__ ap =
            Wcbf + (size_t)(gb + mt * 16 + col) * KP + quad * 8;
        #pragma unroll
        for (int ks = 0; ks < 3; ++ks) A[mt][ks] = *(const short8*)(ap + ks * 32);
    }

    float p[2][4][4];   // conv3 partials [mt][r][o]
    #pragma unroll
    for (int mt = 0; mt < 2; ++mt)
        #pragma unroll
        for (int r = 0; r < 4; ++r)
            #pragma unroll
            for (int o = 0; o < 4; ++o) p[mt][r][o] = 0.f;

    const unsigned short* __restrict__ xrow = xs + col * XST + quad * 8;
    const unsigned short* __restrict__ wb0 =
        w3tb + ((size_t)(gb + quad * 4) * HWP + col) * 4;
    const unsigned short* __restrict__ wb1 =
        w3tb + ((size_t)(gb + 16 + quad * 4) * HWP + col) * 4;

    __syncthreads();   // staging complete

    #pragma unroll 1
    for (int nt = 0; nt < 13; ++nt) {
        ushort4v wv0[4], wv1[4];
        #pragma unroll
        for (int r = 0; r < 4; ++r) {
            wv0[r] = *(const ushort4v*)(wb0 + ((size_t)r * HWP + nt * 16) * 4);
            wv1[r] = *(const ushort4v*)(wb1 + ((size_t)r * HWP + nt * 16) * 4);
        }
        const unsigned short* __restrict__ xp = xrow + nt * 16 * XST;
        const short8 x0 = *(const short8*)(xp);
        const short8 x1 = *(const short8*)(xp + 32);
        const short8 x2 = *(const short8*)(xp + 64);
        floatx4 a0 = {0.f, 0.f, 0.f, 0.f}, a1 = {0.f, 0.f, 0.f, 0.f};
        a0 = __builtin_amdgcn_mfma_f32_16x16x32_bf16(A[0][0], x0, a0, 0, 0, 0);
        a0 = __builtin_amdgcn_mfma_f32_16x16x32_bf16(A[0][1], x1, a0, 0, 0, 0);
        a0 = __builtin_amdgcn_mfma_f32_16x16x32_bf16(A[0][2], x2, a0, 0, 0, 0);
        a1 = __builtin_amdgcn_mfma_f32_16x16x32_bf16(A[1][0], x0, a1, 0, 0, 0);
        a1 = __builtin_amdgcn_mfma_f32_16x16x32_bf16(A[1][1], x1, a1, 0, 0, 0);
        a1 = __builtin_amdgcn_mfma_f32_16x16x32_bf16(A[1][2], x2, a1, 0, 0, 0);
        // conv3 partials; C/D: col(hw)=lane&15, row(g)=quad*4+r  [m89-verified]
        #pragma unroll
        for (int r = 0; r < 4; ++r) {
            p[0][r][0] = fmaf(a0[r], b2f(wv0[r][0]), p[0][r][0]);
            p[0][r][1] = fmaf(a0[r], b2f(wv0[r][1]), p[0][r][1]);
            p[0][r][2] = fmaf(a0[r], b2f(wv0[r][2]), p[0][r][2]);
            p[0][r][3] = fmaf(a0[r], b2f(wv0[r][3]), p[0][r][3]);
            p[1][r][0] = fmaf(a1[r], b2f(wv1[r][0]), p[1][r][0]);
            p[1][r][1] = fmaf(a1[r], b2f(wv1[r][1]), p[1][r][1]);
            p[1][r][2] = fmaf(a1[r], b2f(wv1[r][2]), p[1][r][2]);
            p[1][r][3] = fmaf(a1[r], b2f(wv1[r][3]), p[1][r][3]);
        }
    }

    // reduce over 16 hw-lanes, relu -> gl[2048]
    #pragma unroll
    for (int mt = 0; mt < 2; ++mt)
        #pragma unroll
        for (int r = 0; r < 4; ++r) {
            float q0 = p[mt][r][0], q1 = p[mt][r][1], q2 = p[mt][r][2], q3 = p[mt][r][3];
            #pragma unroll
            for (int s = 8; s >= 1; s >>= 1) {
                q0 += __shfl_down(q0, s, 16);
                q1 += __shfl_down(q1, s, 16);
                q2 += __shfl_down(q2, s, 16);
                q3 += __shfl_down(q3, s, 16);
            }
            if (col == 0) {
                const int glocal = gb + mt * 16 + quad * 4 + r;
                floatx4 ov = {fmaxf(q0, 0.f), fmaxf(q1, 0.f), fmaxf(q2, 0.f), fmaxf(q3, 0.f)};
                *(floatx4*)(gl + glocal * 4) = ov;
            }
        }
    __syncthreads();

    // fc entirely in-block: 640 threads = 80 l x 8 k-parts of 256, then combine
    float* pf = (float*)xs;   // reuse staging LDS (all xs reads done)
    if (t < 640) {
        const int l = t % CIN, part = t / CIN;
        const unsigned short* __restrict__ fr = fctb + (size_t)(part * 256) * CIN + l;
        const float* __restrict__ gp = gl + part * 256;
        float s = 0.f;
        #pragma unroll 4
        for (int kk = 0; kk < 256; ++kk)
            s = fmaf(gp[kk], b2f(fr[(size_t)kk * CIN]), s);
        pf[t] = s;
    }
    __syncthreads();
    if (t < CIN) {
        float s = fc_b[t];
        #pragma unroll
        for (int j = 0; j < 8; ++j) s += pf[j * CIN + t];
        out[b * CIN + t] = s;      // single write, no atomics, no out-init needed
    }
}

extern "C" void kernel_launch(void* const* d_in, const int* in_sizes, int n_in,
                              void* d_out, int out_size, void* d_ws, size_t ws_size,
                              hipStream_t stream) {
    const float* x    = (const float*)d_in[0];
    const float* w1   = (const float*)d_in[1];
    const float* b1   = (const float*)d_in[2];
    const float* w2   = (const float*)d_in[3];
    const float* b2   = (const float*)d_in[4];
    const float* w3   = (const float*)d_in[5];
    const float* fc_w = (const float*)d_in[6];
    const float* fc_b = (const float*)d_in[7];
    float* out = (float*)d_out;

    const int B = in_sizes[0] / (CIN * NSP);   // 256

    // workspace: Wcf8 | Wcbf | w3tb | fctb  (~2.9 MB)
    char* ws = (char*)d_ws;
    float* Wcf8 = (float*)ws;                                   // 8*512*96*4
    size_t off = (size_t)8 * 512 * KP * 4;
    unsigned short* Wcbf = (unsigned short*)(ws + off); off += 512 * KP * 2;
    unsigned short* w3tb = (unsigned short*)(ws + off); off += (size_t)512 * HWP * 4 * 2;
    unsigned short* fctb = (unsigned short*)(ws + off);         // 2048*80*2

    kPre<<<NBA + NBC + NBD, 384, 0, stream>>>(w1, b1, w2, w3, fc_w, Wcf8, w3tb, fctb);
    kRed<<<48, 1024, 0, stream>>>(Wcf8, b2, Wcbf);
    kM<<<B, 1024, 0, stream>>>(x, Wcbf, w3tb, fctb, fc_b, out);
}

// Round 12
// 117.942 us; speedup vs baseline: 1.1892x; 1.0963x over previous
//
#include <hip/hip_runtime.h>
#include <hip/hip_bf16.h>

// B=256, x:[B,80,14,14] f32, w1:[512,80], b1:[512], w2:[512,512], b2:[512],
// w3:[512,4,14,14], fc_w:[80,2048], fc_b:[80] -> out:[B,80] f32.
// h2 = (w2@w1) x + (w2@b1+b2); bias folded as k-channel 80 (x col 80 = 1.0).
#define CIN 80
#define NSP 196
#define HWP 208        // hw padded 196->208 (13 n-tiles of 16)
#define KP  96         // k padded 80(+bias)->96 (3 MFMA k-steps of 32)
#define XST 104        // xs LDS row stride (ushorts)

#define NBA 1024       // Wc partials: 128 o-quads x 8 k-chunks of 64 (atomic-free)
#define NBC 512        // w3 -> bf16 transpose
#define NBD 64         // fc_w -> bf16 convert (SAME layout [l][k])

typedef __attribute__((ext_vector_type(8))) short  short8;
typedef __attribute__((ext_vector_type(4))) float  floatx4;
typedef __attribute__((ext_vector_type(4))) unsigned short ushort4v;
typedef __attribute__((ext_vector_type(8))) unsigned short ushort8v;

static __device__ __forceinline__ unsigned short f2b(float f) {
    __hip_bfloat16 h = __float2bfloat16(f);
    return *(unsigned short*)&h;
}
static __device__ __forceinline__ float b2f(unsigned short u) {
    unsigned int x = ((unsigned int)u) << 16;
    float f; __builtin_memcpy(&f, &x, 4); return f;
}

// ---- kPre: Wc k-split partials (no atomics) + w3 transpose + fc convert -----
__global__ __launch_bounds__(384) void kPre(
    const float* __restrict__ w1, const float* __restrict__ b1,
    const float* __restrict__ w2, const float* __restrict__ w3,
    const float* __restrict__ fc_w,
    float* __restrict__ Wcf8, unsigned short* __restrict__ w3tb,
    unsigned short* __restrict__ fcl)
{
    const int blk = blockIdx.x, t = threadIdx.x;

    if (blk < NBA) {
        // Wcf8[kc][o][lc] = w2[o][m0:m0+64] @ (w1|b1)[m0:m0+64][lc]
        const int o4 = blk >> 3, kc = blk & 7, m0 = kc * 64;
        if (t < 324) {
            const int lc = t % 81, oi = t / 81;
            const int o = o4 * 4 + oi;
            const float* __restrict__ w2p = w2 + (size_t)o * 512 + m0;  // broadcast
            float part = 0.f;
            if (lc < CIN) {
                const float* __restrict__ w1p = w1 + (size_t)m0 * CIN + lc;
                #pragma unroll 8
                for (int i = 0; i < 64; ++i)
                    part = fmaf(w2p[i], w1p[(size_t)i * CIN], part);
            } else {
                #pragma unroll 8
                for (int i = 0; i < 64; ++i)
                    part = fmaf(w2p[i], b1[m0 + i], part);
            }
            Wcf8[((size_t)kc * 512 + o) * KP + lc] = part;   // only lc<=80 written
        }
    } else if (blk < NBA + NBC) {
        // w3 [g][4][196] -> w3tb [g][208][4] bf16, hw zero-padded
        const int g = blk - NBA;
        if (t < HWP) {
            ushort4v v;
            #pragma unroll
            for (int o = 0; o < 4; ++o)
                v[o] = f2b((t < NSP) ? w3[(size_t)g * 4 * NSP + o * NSP + t] : 0.f);
            *(ushort4v*)(w3tb + ((size_t)g * HWP + t) * 4) = v;
        }
    } else {
        // fc_w [80][2048] f32 -> fcl [80][2048] bf16 (elementwise, coalesced)
        const int base = (blk - NBA - NBC) * 2560;   // 64 blocks * 2560 = 163840
        for (int i = t; i < 2560; i += 384) {
            const int idx = base + i;
            fcl[idx] = f2b(fc_w[idx]);
        }
    }
}

// ---- kRed: Wcbf[512][96] bf16 = sum of 8 partials (+b2 on col 80, 0 pads) ---
__global__ __launch_bounds__(1024) void kRed(
    const float* __restrict__ Wcf8, const float* __restrict__ b2,
    unsigned short* __restrict__ Wcbf)
{
    const int idx = blockIdx.x * 1024 + threadIdx.x;   // 48 blocks = 512*96
    const int o = idx / KP, c = idx - o * KP;
    float s = 0.f;
    if (c <= CIN) {
        #pragma unroll
        for (int j = 0; j < 8; ++j)
            s += Wcf8[((size_t)j * 512 + o) * KP + c];
        if (c == CIN) s += b2[o];
    }
    Wcbf[idx] = f2b(s);
}

// ---- kM: one block per batch, ALL 512 groups. 1024 thr = 16 waves x 32 grp. -
// R12 fix: fc tail uses per-thread VECTOR loads from fcl[l][k] (was 256 serial
// scalar loads -> ~30us hidden tail); x staging uses float4 loads.
__global__ __launch_bounds__(1024) void kM(
    const float* __restrict__ x, const unsigned short* __restrict__ Wcbf,
    const unsigned short* __restrict__ w3tb, const unsigned short* __restrict__ fcl,
    const float* __restrict__ fc_b, float* __restrict__ out)
{
    __shared__ __align__(16) unsigned short xs[HWP * XST];  // 43264 B
    __shared__ float gl[2048];                              // 8192 B
    const int b = blockIdx.x, t = threadIdx.x;

    // stage x[b]: [k][hw] f32 (float4: 196 = 49 quads, no row-crossing) -> xs[hw][k]
    {
        const floatx4* __restrict__ xb4 = (const floatx4*)(x + (size_t)b * CIN * NSP);
        for (int i4 = t; i4 < CIN * 49; i4 += 1024) {
            const int k = i4 / 49, hw4 = (i4 - k * 49) * 4;
            const floatx4 v = xb4[i4];
            xs[(hw4 + 0) * XST + k] = f2b(v[0]);
            xs[(hw4 + 1) * XST + k] = f2b(v[1]);
            xs[(hw4 + 2) * XST + k] = f2b(v[2]);
            xs[(hw4 + 3) * XST + k] = f2b(v[3]);
        }
        // k = 80 -> 1.0 (bias channel), 81..103 -> 0, for hw < 196
        for (int idx = t; idx < NSP * 24; idx += 1024) {
            const int hw = idx / 24, k = 80 + (idx - (idx / 24) * 24);
            xs[hw * XST + k] = (k == CIN) ? (unsigned short)0x3F80 : (unsigned short)0;
        }
        // hw pad rows 196..207: all-zero
        for (int idx = t; idx < 12 * XST; idx += 1024) {
            const int hw = NSP + idx / XST, k = idx - (idx / XST) * XST;
            xs[hw * XST + k] = 0;
        }
    }

    const int w = t >> 6, lane = t & 63;
    const int col = lane & 15, quad = lane >> 4;
    const int gb = w * 32;                 // wave's group base (16 waves x 32 = 512)

    // A-frags: 2 m-tiles x 96 k, bf16 (24 VGPRs), from L2-hot Wcbf
    short8 A[2][3];
    #pragma unroll
    for (int mt = 0; mt < 2; ++mt) {
        const unsigned short* __restrict__ ap =
            Wcbf + (size_t)(gb + mt * 16 + col) * KP + quad * 8;
        #pragma unroll
        for (int ks = 0; ks < 3; ++ks) A[mt][ks] = *(const short8*)(ap + ks * 32);
    }

    float p[2][4][4];   // conv3 partials [mt][r][o]
    #pragma unroll
    for (int mt = 0; mt < 2; ++mt)
        #pragma unroll
        for (int r = 0; r < 4; ++r)
            #pragma unroll
            for (int o = 0; o < 4; ++o) p[mt][r][o] = 0.f;

    const unsigned short* __restrict__ xrow = xs + col * XST + quad * 8;
    const unsigned short* __restrict__ wb0 =
        w3tb + ((size_t)(gb + quad * 4) * HWP + col) * 4;
    const unsigned short* __restrict__ wb1 =
        w3tb + ((size_t)(gb + 16 + quad * 4) * HWP + col) * 4;

    __syncthreads();   // staging complete

    #pragma unroll 1
    for (int nt = 0; nt < 13; ++nt) {
        ushort4v wv0[4], wv1[4];
        #pragma unroll
        for (int r = 0; r < 4; ++r) {
            wv0[r] = *(const ushort4v*)(wb0 + ((size_t)r * HWP + nt * 16) * 4);
            wv1[r] = *(const ushort4v*)(wb1 + ((size_t)r * HWP + nt * 16) * 4);
        }
        const unsigned short* __restrict__ xp = xrow + nt * 16 * XST;
        const short8 x0 = *(const short8*)(xp);
        const short8 x1 = *(const short8*)(xp + 32);
        const short8 x2 = *(const short8*)(xp + 64);
        floatx4 a0 = {0.f, 0.f, 0.f, 0.f}, a1 = {0.f, 0.f, 0.f, 0.f};
        a0 = __builtin_amdgcn_mfma_f32_16x16x32_bf16(A[0][0], x0, a0, 0, 0, 0);
        a0 = __builtin_amdgcn_mfma_f32_16x16x32_bf16(A[0][1], x1, a0, 0, 0, 0);
        a0 = __builtin_amdgcn_mfma_f32_16x16x32_bf16(A[0][2], x2, a0, 0, 0, 0);
        a1 = __builtin_amdgcn_mfma_f32_16x16x32_bf16(A[1][0], x0, a1, 0, 0, 0);
        a1 = __builtin_amdgcn_mfma_f32_16x16x32_bf16(A[1][1], x1, a1, 0, 0, 0);
        a1 = __builtin_amdgcn_mfma_f32_16x16x32_bf16(A[1][2], x2, a1, 0, 0, 0);
        // conv3 partials; C/D: col(hw)=lane&15, row(g)=quad*4+r  [m89-verified]
        #pragma unroll
        for (int r = 0; r < 4; ++r) {
            p[0][r][0] = fmaf(a0[r], b2f(wv0[r][0]), p[0][r][0]);
            p[0][r][1] = fmaf(a0[r], b2f(wv0[r][1]), p[0][r][1]);
            p[0][r][2] = fmaf(a0[r], b2f(wv0[r][2]), p[0][r][2]);
            p[0][r][3] = fmaf(a0[r], b2f(wv0[r][3]), p[0][r][3]);
            p[1][r][0] = fmaf(a1[r], b2f(wv1[r][0]), p[1][r][0]);
            p[1][r][1] = fmaf(a1[r], b2f(wv1[r][1]), p[1][r][1]);
            p[1][r][2] = fmaf(a1[r], b2f(wv1[r][2]), p[1][r][2]);
            p[1][r][3] = fmaf(a1[r], b2f(wv1[r][3]), p[1][r][3]);
        }
    }

    // reduce over 16 hw-lanes, relu -> gl[2048]
    #pragma unroll
    for (int mt = 0; mt < 2; ++mt)
        #pragma unroll
        for (int r = 0; r < 4; ++r) {
            float q0 = p[mt][r][0], q1 = p[mt][r][1], q2 = p[mt][r][2], q3 = p[mt][r][3];
            #pragma unroll
            for (int s = 8; s >= 1; s >>= 1) {
                q0 += __shfl_down(q0, s, 16);
                q1 += __shfl_down(q1, s, 16);
                q2 += __shfl_down(q2, s, 16);
                q3 += __shfl_down(q3, s, 16);
            }
            if (col == 0) {
                const int glocal = gb + mt * 16 + quad * 4 + r;
                floatx4 ov = {fmaxf(q0, 0.f), fmaxf(q1, 0.f), fmaxf(q2, 0.f), fmaxf(q3, 0.f)};
                *(floatx4*)(gl + glocal * 4) = ov;
            }
        }
    __syncthreads();

    // fc in-block: 640 thr = 80 l x 8 k-parts of 256; per-thread 32 VECTOR loads
    // from fcl[l][k] (contiguous run), gl reads are wave-broadcast.
    float* pf = (float*)xs;   // reuse staging LDS
    if (t < 640) {
        const int l = t % CIN, part = t / CIN;
        const unsigned short* __restrict__ fr = fcl + (size_t)l * 2048 + part * 256;
        const float* __restrict__ gp = gl + part * 256;
        float s = 0.f;
        #pragma unroll 8
        for (int j = 0; j < 32; ++j) {
            const ushort8v u = *(const ushort8v*)(fr + j * 8);
            const floatx4 g0 = *(const floatx4*)(gp + j * 8);
            const floatx4 g1 = *(const floatx4*)(gp + j * 8 + 4);
            s = fmaf(g0[0], b2f(u[0]), s);
            s = fmaf(g0[1], b2f(u[1]), s);
            s = fmaf(g0[2], b2f(u[2]), s);
            s = fmaf(g0[3], b2f(u[3]), s);
            s = fmaf(g1[0], b2f(u[4]), s);
            s = fmaf(g1[1], b2f(u[5]), s);
            s = fmaf(g1[2], b2f(u[6]), s);
            s = fmaf(g1[3], b2f(u[7]), s);
        }
        pf[t] = s;
    }
    __syncthreads();
    if (t < CIN) {
        float s = fc_b[t];
        #pragma unroll
        for (int j = 0; j < 8; ++j) s += pf[j * CIN + t];
        out[b * CIN + t] = s;      // single write, no atomics
    }
}

extern "C" void kernel_launch(void* const* d_in, const int* in_sizes, int n_in,
                              void* d_out, int out_size, void* d_ws, size_t ws_size,
                              hipStream_t stream) {
    const float* x    = (const float*)d_in[0];
    const float* w1   = (const float*)d_in[1];
    const float* b1   = (const float*)d_in[2];
    const float* w2   = (const float*)d_in[3];
    const float* b2   = (const float*)d_in[4];
    const float* w3   = (const float*)d_in[5];
    const float* fc_w = (const float*)d_in[6];
    const float* fc_b = (const float*)d_in[7];
    float* out = (float*)d_out;

    const int B = in_sizes[0] / (CIN * NSP);   // 256

    // workspace: Wcf8 | Wcbf | w3tb | fcl  (~2.9 MB)
    char* ws = (char*)d_ws;
    float* Wcf8 = (float*)ws;                                   // 8*512*96*4
    size_t off = (size_t)8 * 512 * KP * 4;
    unsigned short* Wcbf = (unsigned short*)(ws + off); off += 512 * KP * 2;
    unsigned short* w3tb = (unsigned short*)(ws + off); off += (size_t)512 * HWP * 4 * 2;
    unsigned short* fcl  = (unsigned short*)(ws + off);         // 80*2048*2

    kPre<<<NBA + NBC + NBD, 384, 0, stream>>>(w1, b1, w2, w3, fc_w, Wcf8, w3tb, fcl);
    kRed<<<48, 1024, 0, stream>>>(Wcf8, b2, Wcbf);
    kM<<<B, 1024, 0, stream>>>(x, Wcbf, w3tb, fcl, fc_b, out);
}

// Round 13
// 113.459 us; speedup vs baseline: 1.2362x; 1.0395x over previous
//
#include <hip/hip_runtime.h>
#include <hip/hip_bf16.h>

// B=256, x:[B,80,14,14] f32, w1:[512,80], b1:[512], w2:[512,512], b2:[512],
// w3:[512,4,14,14], fc_w:[80,2048], fc_b:[80] -> out:[B,80] f32.
// h2 = (w2@w1) x + (w2@b1+b2); bias folded as k-channel 80 (x col 80 = 1.0).
#define CIN 80
#define NSP 196
#define HWP 208        // hw padded 196->208 (13 n-tiles of 16)
#define KP  96         // k padded 80(+bias)->96 (3 MFMA k-steps of 32)
#define XST 104        // xs LDS row stride (ushorts)

#define NBA 1024       // Wc partials: 128 o-quads x 8 k-chunks of 64 (atomic-free)
#define NBC 512        // w3 -> bf16 transpose
#define NBD 64         // fc_w -> bf16 convert (same [l][k] layout)

typedef __attribute__((ext_vector_type(8))) short  short8;
typedef __attribute__((ext_vector_type(4))) float  floatx4;
typedef __attribute__((ext_vector_type(4))) unsigned short ushort4v;

static __device__ __forceinline__ unsigned short f2b(float f) {
    __hip_bfloat16 h = __float2bfloat16(f);
    return *(unsigned short*)&h;
}
static __device__ __forceinline__ float b2f(unsigned short u) {
    unsigned int x = ((unsigned int)u) << 16;
    float f; __builtin_memcpy(&f, &x, 4); return f;
}

// ---- kPre: Wc k-split partials (no atomics) + w3 transpose + fc convert -----
__global__ __launch_bounds__(384) void kPre(
    const float* __restrict__ w1, const float* __restrict__ b1,
    const float* __restrict__ w2, const float* __restrict__ w3,
    const float* __restrict__ fc_w,
    float* __restrict__ Wcf8, unsigned short* __restrict__ w3tb,
    unsigned short* __restrict__ fcl)
{
    const int blk = blockIdx.x, t = threadIdx.x;

    if (blk < NBA) {
        // Wcf8[kc][o][lc] = w2[o][m0:m0+64] @ (w1|b1)[m0:m0+64][lc]
        const int o4 = blk >> 3, kc = blk & 7, m0 = kc * 64;
        if (t < 324) {
            const int lc = t % 81, oi = t / 81;
            const int o = o4 * 4 + oi;
            const float* __restrict__ w2p = w2 + (size_t)o * 512 + m0;  // broadcast
            float part = 0.f;
            if (lc < CIN) {
                const float* __restrict__ w1p = w1 + (size_t)m0 * CIN + lc;
                #pragma unroll 8
                for (int i = 0; i < 64; ++i)
                    part = fmaf(w2p[i], w1p[(size_t)i * CIN], part);
            } else {
                #pragma unroll 8
                for (int i = 0; i < 64; ++i)
                    part = fmaf(w2p[i], b1[m0 + i], part);
            }
            Wcf8[((size_t)kc * 512 + o) * KP + lc] = part;   // only lc<=80 written
        }
    } else if (blk < NBA + NBC) {
        // w3 [g][4][196] -> w3tb [g][208][4] bf16, hw zero-padded
        const int g = blk - NBA;
        if (t < HWP) {
            ushort4v v;
            #pragma unroll
            for (int o = 0; o < 4; ++o)
                v[o] = f2b((t < NSP) ? w3[(size_t)g * 4 * NSP + o * NSP + t] : 0.f);
            *(ushort4v*)(w3tb + ((size_t)g * HWP + t) * 4) = v;
        }
    } else {
        // fc_w [80][2048] f32 -> fcl [80][2048] bf16 (elementwise, coalesced)
        const int base = (blk - NBA - NBC) * 2560;   // 64 blocks * 2560 = 163840
        for (int i = t; i < 2560; i += 384) {
            const int idx = base + i;
            fcl[idx] = f2b(fc_w[idx]);
        }
    }
}

// ---- kRed: Wcbf[512][96] bf16 = sum of 8 partials (+b2 on col 80, 0 pads) ---
__global__ __launch_bounds__(1024) void kRed(
    const float* __restrict__ Wcf8, const float* __restrict__ b2,
    unsigned short* __restrict__ Wcbf)
{
    const int idx = blockIdx.x * 1024 + threadIdx.x;   // 48 blocks = 512*96
    const int o = idx / KP, c = idx - o * KP;
    float s = 0.f;
    if (c <= CIN) {
        #pragma unroll
        for (int j = 0; j < 8; ++j)
            s += Wcf8[((size_t)j * 512 + o) * KP + c];
        if (c == CIN) s += b2[o];
    }
    Wcbf[idx] = f2b(s);
}

// ---- kM: one block per batch, ALL 512 groups. 1024 thr = 16 waves x 32 grp. -
// R13 fix: fc tail is wave-per-l-row — lane-contiguous fcl reads (256 B/instr,
// was 64 cache lines/instr), gl LDS reads 2-way (free), width-64 shfl reduce.
__global__ __launch_bounds__(1024) void kM(
    const float* __restrict__ x, const unsigned short* __restrict__ Wcbf,
    const unsigned short* __restrict__ w3tb, const unsigned short* __restrict__ fcl,
    const float* __restrict__ fc_b, float* __restrict__ out)
{
    __shared__ __align__(16) unsigned short xs[HWP * XST];  // 43264 B
    __shared__ float gl[2048];                              // 8192 B
    const int b = blockIdx.x, t = threadIdx.x;

    // stage x[b]: [k][hw] f32 (float4: 49 quads/row, no row-crossing) -> xs[hw][k]
    {
        const floatx4* __restrict__ xb4 = (const floatx4*)(x + (size_t)b * CIN * NSP);
        for (int i4 = t; i4 < CIN * 49; i4 += 1024) {
            const int k = i4 / 49, hw4 = (i4 - k * 49) * 4;
            const floatx4 v = xb4[i4];
            xs[(hw4 + 0) * XST + k] = f2b(v[0]);
            xs[(hw4 + 1) * XST + k] = f2b(v[1]);
            xs[(hw4 + 2) * XST + k] = f2b(v[2]);
            xs[(hw4 + 3) * XST + k] = f2b(v[3]);
        }
        // k = 80 -> 1.0 (bias channel), 81..103 -> 0, for hw < 196
        for (int idx = t; idx < NSP * 24; idx += 1024) {
            const int hw = idx / 24, k = 80 + (idx - (idx / 24) * 24);
            xs[hw * XST + k] = (k == CIN) ? (unsigned short)0x3F80 : (unsigned short)0;
        }
        // hw pad rows 196..207: all-zero
        for (int idx = t; idx < 12 * XST; idx += 1024) {
            const int hw = NSP + idx / XST, k = idx - (idx / XST) * XST;
            xs[hw * XST + k] = 0;
        }
    }

    const int w = t >> 6, lane = t & 63;
    const int col = lane & 15, quad = lane >> 4;
    const int gb = w * 32;                 // wave's group base (16 waves x 32 = 512)

    // A-frags: 2 m-tiles x 96 k, bf16 (24 VGPRs), from L2-hot Wcbf
    short8 A[2][3];
    #pragma unroll
    for (int mt = 0; mt < 2; ++mt) {
        const unsigned short* __restrict__ ap =
            Wcbf + (size_t)(gb + mt * 16 + col) * KP + quad * 8;
        #pragma unroll
        for (int ks = 0; ks < 3; ++ks) A[mt][ks] = *(const short8*)(ap + ks * 32);
    }

    float p[2][4][4];   // conv3 partials [mt][r][o]
    #pragma unroll
    for (int mt = 0; mt < 2; ++mt)
        #pragma unroll
        for (int r = 0; r < 4; ++r)
            #pragma unroll
            for (int o = 0; o < 4; ++o) p[mt][r][o] = 0.f;

    const unsigned short* __restrict__ xrow = xs + col * XST + quad * 8;
    const unsigned short* __restrict__ wb0 =
        w3tb + ((size_t)(gb + quad * 4) * HWP + col) * 4;
    const unsigned short* __restrict__ wb1 =
        w3tb + ((size_t)(gb + 16 + quad * 4) * HWP + col) * 4;

    __syncthreads();   // staging complete

    #pragma unroll 1
    for (int nt = 0; nt < 13; ++nt) {
        ushort4v wv0[4], wv1[4];
        #pragma unroll
        for (int r = 0; r < 4; ++r) {
            wv0[r] = *(const ushort4v*)(wb0 + ((size_t)r * HWP + nt * 16) * 4);
            wv1[r] = *(const ushort4v*)(wb1 + ((size_t)r * HWP + nt * 16) * 4);
        }
        const unsigned short* __restrict__ xp = xrow + nt * 16 * XST;
        const short8 x0 = *(const short8*)(xp);
        const short8 x1 = *(const short8*)(xp + 32);
        const short8 x2 = *(const short8*)(xp + 64);
        floatx4 a0 = {0.f, 0.f, 0.f, 0.f}, a1 = {0.f, 0.f, 0.f, 0.f};
        a0 = __builtin_amdgcn_mfma_f32_16x16x32_bf16(A[0][0], x0, a0, 0, 0, 0);
        a0 = __builtin_amdgcn_mfma_f32_16x16x32_bf16(A[0][1], x1, a0, 0, 0, 0);
        a0 = __builtin_amdgcn_mfma_f32_16x16x32_bf16(A[0][2], x2, a0, 0, 0, 0);
        a1 = __builtin_amdgcn_mfma_f32_16x16x32_bf16(A[1][0], x0, a1, 0, 0, 0);
        a1 = __builtin_amdgcn_mfma_f32_16x16x32_bf16(A[1][1], x1, a1, 0, 0, 0);
        a1 = __builtin_amdgcn_mfma_f32_16x16x32_bf16(A[1][2], x2, a1, 0, 0, 0);
        // conv3 partials; C/D: col(hw)=lane&15, row(g)=quad*4+r  [m89-verified]
        #pragma unroll
        for (int r = 0; r < 4; ++r) {
            p[0][r][0] = fmaf(a0[r], b2f(wv0[r][0]), p[0][r][0]);
            p[0][r][1] = fmaf(a0[r], b2f(wv0[r][1]), p[0][r][1]);
            p[0][r][2] = fmaf(a0[r], b2f(wv0[r][2]), p[0][r][2]);
            p[0][r][3] = fmaf(a0[r], b2f(wv0[r][3]), p[0][r][3]);
            p[1][r][0] = fmaf(a1[r], b2f(wv1[r][0]), p[1][r][0]);
            p[1][r][1] = fmaf(a1[r], b2f(wv1[r][1]), p[1][r][1]);
            p[1][r][2] = fmaf(a1[r], b2f(wv1[r][2]), p[1][r][2]);
            p[1][r][3] = fmaf(a1[r], b2f(wv1[r][3]), p[1][r][3]);
        }
    }

    // reduce over 16 hw-lanes, relu -> gl[2048]
    #pragma unroll
    for (int mt = 0; mt < 2; ++mt)
        #pragma unroll
        for (int r = 0; r < 4; ++r) {
            float q0 = p[mt][r][0], q1 = p[mt][r][1], q2 = p[mt][r][2], q3 = p[mt][r][3];
            #pragma unroll
            for (int s = 8; s >= 1; s >>= 1) {
                q0 += __shfl_down(q0, s, 16);
                q1 += __shfl_down(q1, s, 16);
                q2 += __shfl_down(q2, s, 16);
                q3 += __shfl_down(q3, s, 16);
            }
            if (col == 0) {
                const int glocal = gb + mt * 16 + quad * 4 + r;
                floatx4 ov = {fmaxf(q0, 0.f), fmaxf(q1, 0.f), fmaxf(q2, 0.f), fmaxf(q3, 0.f)};
                *(floatx4*)(gl + glocal * 4) = ov;
            }
        }
    __syncthreads();

    // fc: wave per l-row (16 waves x 5 rows = 80). Lane ell reads ushort2 at
    // fcl[l][j*128+2*ell] -> 256 B contiguous per instr; gl LDS 2-way (free);
    // bf16 decode = shift/and; width-64 shuffle reduce.
    #pragma unroll 1
    for (int rr = 0; rr < 5; ++rr) {
        const int l = w * 5 + rr;
        const unsigned int* __restrict__ fr =
            (const unsigned int*)(fcl + (size_t)l * 2048) + lane;
        const float* __restrict__ gp = gl + lane * 2;
        float s = 0.f;
        #pragma unroll
        for (int j = 0; j < 16; ++j) {
            const unsigned int u = fr[j * 64];
            float lo, hi;
            { unsigned int a = u << 16;          __builtin_memcpy(&lo, &a, 4); }
            { unsigned int a = u & 0xFFFF0000u;  __builtin_memcpy(&hi, &a, 4); }
            s = fmaf(gp[j * 128    ], lo, s);
            s = fmaf(gp[j * 128 + 1], hi, s);
        }
        #pragma unroll
        for (int sft = 32; sft >= 1; sft >>= 1) s += __shfl_down(s, sft, 64);
        if (lane == 0) out[b * CIN + l] = s + fc_b[l];
    }
}

extern "C" void kernel_launch(void* const* d_in, const int* in_sizes, int n_in,
                              void* d_out, int out_size, void* d_ws, size_t ws_size,
                              hipStream_t stream) {
    const float* x    = (const float*)d_in[0];
    const float* w1   = (const float*)d_in[1];
    const float* b1   = (const float*)d_in[2];
    const float* w2   = (const float*)d_in[3];
    const float* b2   = (const float*)d_in[4];
    const float* w3   = (const float*)d_in[5];
    const float* fc_w = (const float*)d_in[6];
    const float* fc_b = (const float*)d_in[7];
    float* out = (float*)d_out;

    const int B = in_sizes[0] / (CIN * NSP);   // 256

    // workspace: Wcf8 | Wcbf | w3tb | fcl  (~2.9 MB)
    char* ws = (char*)d_ws;
    float* Wcf8 = (float*)ws;                                   // 8*512*96*4
    size_t off = (size_t)8 * 512 * KP * 4;
    unsigned short* Wcbf = (unsigned short*)(ws + off); off += 512 * KP * 2;
    unsigned short* w3tb = (unsigned short*)(ws + off); off += (size_t)512 * HWP * 4 * 2;
    unsigned short* fcl  = (unsigned short*)(ws + off);         // 80*2048*2

    kPre<<<NBA + NBC + NBD, 384, 0, stream>>>(w1, b1, w2, w3, fc_w, Wcf8, w3tb, fcl);
    kRed<<<48, 1024, 0, stream>>>(Wcf8, b2, Wcbf);
    kM<<<B, 1024, 0, stream>>>(x, Wcbf, w3tb, fcl, fc_b, out);
}